// Round 1
// baseline (260.582 us; speedup 1.0000x reference)
//
#include <hip/hip_runtime.h>
#include <math.h>

typedef unsigned short u16;
typedef unsigned int u32;
typedef __attribute__((ext_vector_type(8))) short short8;      // 8 bf16 (4 VGPRs) MFMA A/B frag
typedef __attribute__((ext_vector_type(8))) _Float16 half8;    // 8 f16 MFMA A/B frag
typedef __attribute__((ext_vector_type(4))) float f32x4;       // MFMA C/D frag

#define EPS 1e-8f

// ---------- helpers ----------
__device__ inline float bf2f(u16 u) {
    union { u32 i; float f; } v; v.i = ((u32)u) << 16; return v.f;
}
__device__ inline u16 f2bf(float f) {  // RNE
    union { float f; u32 u; } v; v.f = f;
    u32 r = v.u + 0x7fffu + ((v.u >> 16) & 1u);
    return (u16)(r >> 16);
}
__device__ inline u16 f2h(float f) {   // f32 -> f16 RNE
    _Float16 h = (_Float16)f;
    union { _Float16 hh; u16 u; } v; v.hh = h; return v.u;
}
__device__ inline u32 pack2(float a, float b) {
    return (u32)f2bf(a) | ((u32)f2bf(b) << 16);
}
__device__ inline float wave_sum(float v) {
    for (int off = 32; off; off >>= 1) v += __shfl_xor(v, off, 64);
    return v;
}

// ---------- K1: prep ----------
// blocks [0,128):    vis rows: fp32-norm + bf16-norm + raw bf16 (+ zero loss/corrSS in bid 0)
// blocks [128,896):  weight cvt fp32->bf16 (wq, wv, wo)
// blocks [896,1024): tm rows 512..1023 -> normalized bf16 negsb[512:]
// blocks [1024,1088): wk -> transposed f16 wkT[j][d]
__global__ __launch_bounds__(256) void prep(const float* __restrict__ vis,
                                            const float* __restrict__ ipw,
                                            const float* __restrict__ opw,
                                            const float* __restrict__ tm,
                                            float* __restrict__ vis_n,
                                            u16* __restrict__ vis_nb,
                                            u16* __restrict__ vis_b,
                                            u16* __restrict__ wqb,
                                            u16* __restrict__ wvb,
                                            u16* __restrict__ wob,
                                            u16* __restrict__ negsb,
                                            u16* __restrict__ wkT,
                                            float* __restrict__ corrSS,
                                            float* __restrict__ loss0)
{
    int bid = blockIdx.x;
    int t = threadIdx.x;
    if (bid >= 1024) {                       // wk transpose -> f16
        __shared__ __align__(16) u16 T[64 * 72];
        int idx = bid - 1024;
        int a = idx >> 3, cb = idx & 7;      // a: d-tile, cb: j-tile
        const float* wk = ipw + 262144;      // rows 512..1023 of in_proj_w
        int r = t >> 2, c0 = (t & 3) * 16;
        #pragma unroll
        for (int q = 0; q < 4; q++) {
            float4 v = *(const float4*)&wk[(size_t)(a * 64 + r) * 512 + cb * 64 + c0 + q * 4];
            T[(c0 + q * 4 + 0) * 72 + r] = f2h(v.x);
            T[(c0 + q * 4 + 1) * 72 + r] = f2h(v.y);
            T[(c0 + q * 4 + 2) * 72 + r] = f2h(v.z);
            T[(c0 + q * 4 + 3) * 72 + r] = f2h(v.w);
        }
        __syncthreads();
        int j = t >> 2, ch = (t & 3) * 16;
        *(uint4*)&wkT[(size_t)(cb * 64 + j) * 512 + a * 64 + ch]     = *(const uint4*)&T[j * 72 + ch];
        *(uint4*)&wkT[(size_t)(cb * 64 + j) * 512 + a * 64 + ch + 8] = *(const uint4*)&T[j * 72 + ch + 8];
        return;
    }
    if (bid >= 896) {                        // tm rows -> normalized negsb[512:]
        int wave = t >> 6, lane = t & 63;
        int j = 512 + (bid - 896) * 4 + wave;
        const float* row = tm + (size_t)j * 512 + lane * 8;
        float4 x0 = *(const float4*)row;
        float4 x1 = *(const float4*)(row + 4);
        float ss = x0.x*x0.x + x0.y*x0.y + x0.z*x0.z + x0.w*x0.w
                 + x1.x*x1.x + x1.y*x1.y + x1.z*x1.z + x1.w*x1.w;
        ss = wave_sum(ss);
        float inv = 1.0f / fmaxf(sqrtf(ss), EPS);
        uint4 pk;
        pk.x = pack2(x0.x*inv, x0.y*inv); pk.y = pack2(x0.z*inv, x0.w*inv);
        pk.z = pack2(x1.x*inv, x1.y*inv); pk.w = pack2(x1.z*inv, x1.w*inv);
        *(uint4*)(negsb + (size_t)j * 512 + lane * 8) = pk;
        return;
    }
    if (bid >= 128) {                        // weight conversions
        int i = ((bid - 128) * 256 + t) * 4;
        const float* src; u16* dst; int j;
        if (i < 262144)      { j = i;          src = ipw + j;          dst = wqb + j; }
        else if (i < 524288) { j = i - 262144; src = ipw + 524288 + j; dst = wvb + j; }
        else                 { j = i - 524288; src = opw + j;          dst = wob + j; }
        float4 v = *(const float4*)src;
        uint2 pk; pk.x = pack2(v.x, v.y); pk.y = pack2(v.z, v.w);
        *(uint2*)dst = pk;
        return;
    }
    if (bid == 0) {
        if (t == 0) loss0[0] = 0.0f;
        corrSS[t] = 0.0f;
        corrSS[t + 256] = 0.0f;
    }
    int wave = t >> 6, lane = t & 63;
    int b = bid * 4 + wave;                  // B = 512
    const float* row = vis + (size_t)b * 512 + lane * 8;
    float4 x0 = *(const float4*)row;
    float4 x1 = *(const float4*)(row + 4);
    uint4 rk;
    rk.x = pack2(x0.x, x0.y); rk.y = pack2(x0.z, x0.w);
    rk.z = pack2(x1.x, x1.y); rk.w = pack2(x1.z, x1.w);
    *(uint4*)(vis_b + (size_t)b * 512 + lane * 8) = rk;
    float ss = x0.x*x0.x + x0.y*x0.y + x0.z*x0.z + x0.w*x0.w
             + x1.x*x1.x + x1.y*x1.y + x1.z*x1.z + x1.w*x1.w;
    ss = wave_sum(ss);
    float inv = 1.0f / fmaxf(sqrtf(ss), EPS);
    float4 y0, y1;
    y0.x = x0.x*inv; y0.y = x0.y*inv; y0.z = x0.z*inv; y0.w = x0.w*inv;
    y1.x = x1.x*inv; y1.y = x1.y*inv; y1.z = x1.z*inv; y1.w = x1.w*inv;
    *(float4*)(vis_n + (size_t)b * 512 + lane * 8)     = y0;
    *(float4*)(vis_n + (size_t)b * 512 + lane * 8 + 4) = y1;
    uint4 pk;
    pk.x = pack2(y0.x, y0.y); pk.y = pack2(y0.z, y0.w);
    pk.z = pack2(y1.x, y1.y); pk.w = pack2(y1.z, y1.w);
    *(uint4*)(vis_nb + (size_t)b * 512 + lane * 8) = pk;
}

// ---------- K2: fused q-proj + qk-proj -> qkb bf16 [(b*8+h)*512 + j] ----------
// grid (8 m-tiles, 8 heads). Phase A: q tile (bf16 MFMA). Phase B: q @ wkT (f16 MFMA).
__global__ __launch_bounds__(256) void qqk(const u16* __restrict__ visb,
                                           const u16* __restrict__ wqb,
                                           const float* __restrict__ ipb,
                                           const u16* __restrict__ wkT,
                                           u16* __restrict__ qkb)
{
    __shared__ __align__(16) u16 As[64 * 72];
    __shared__ __align__(16) u16 Bs[64 * 72];
    __shared__ __align__(16) u16 Qf[64 * 72];   // q tile in f16
    const int t = threadIdx.x, lane = t & 63, w = t >> 6;
    const int m0 = blockIdx.x * 64, h = blockIdx.y;
    const int wm = (w >> 1) * 32, wn = (w & 1) * 32;
    const int l16 = lane & 15, quad = lane >> 4;
    const int srow = t >> 3, scol = (t & 7) * 8;

    f32x4 acc[2][2];
    for (int i = 0; i < 2; i++)
        for (int j = 0; j < 2; j++)
            for (int e = 0; e < 4; e++) acc[i][j][e] = 0.f;

    for (int ko = 0; ko < 512; ko += 64) {
        __syncthreads();
        #pragma unroll
        for (int i = 0; i < 2; i++) {
            int row = i * 32 + srow;
            *(uint4*)&As[row * 72 + scol] = *(const uint4*)&visb[(size_t)(m0 + row) * 512 + ko + scol];
            *(uint4*)&Bs[row * 72 + scol] = *(const uint4*)&wqb[(size_t)(h * 64 + row) * 512 + ko + scol];
        }
        __syncthreads();
        #pragma unroll
        for (int ks = 0; ks < 2; ks++) {
            short8 af[2], bfr[2];
            #pragma unroll
            for (int i = 0; i < 2; i++)
                af[i] = *(const short8*)&As[(wm + i * 16 + l16) * 72 + ks * 32 + quad * 8];
            #pragma unroll
            for (int j = 0; j < 2; j++)
                bfr[j] = *(const short8*)&Bs[(wn + j * 16 + l16) * 72 + ks * 32 + quad * 8];
            #pragma unroll
            for (int i = 0; i < 2; i++)
                #pragma unroll
                for (int j = 0; j < 2; j++)
                    acc[i][j] = __builtin_amdgcn_mfma_f32_16x16x32_bf16(af[i], bfr[j], acc[i][j], 0, 0, 0);
        }
    }
    // epilogue: q (+bq) -> f16 in Qf
    #pragma unroll
    for (int i = 0; i < 2; i++)
        #pragma unroll
        for (int j = 0; j < 2; j++)
            #pragma unroll
            for (int r = 0; r < 4; r++) {
                int rl = wm + i * 16 + quad * 4 + r;
                int cl = wn + j * 16 + l16;
                Qf[rl * 72 + cl] = f2h(acc[i][j][r] + ipb[h * 64 + cl]);
            }
    // Phase B: qk[m][j] = sum_d q[m][d] * wk[h*64+d][j], K=64, 8 j-tiles
    for (int jt = 0; jt < 8; jt++) {
        __syncthreads();
        #pragma unroll
        for (int i = 0; i < 2; i++) {
            int row = i * 32 + srow;
            *(uint4*)&Bs[row * 72 + scol] = *(const uint4*)&wkT[(size_t)(jt * 64 + row) * 512 + h * 64 + scol];
        }
        __syncthreads();
        f32x4 a2[2][2];
        for (int i = 0; i < 2; i++)
            for (int j = 0; j < 2; j++)
                for (int e = 0; e < 4; e++) a2[i][j][e] = 0.f;
        #pragma unroll
        for (int ks = 0; ks < 2; ks++) {
            half8 af[2], bfr[2];
            #pragma unroll
            for (int i = 0; i < 2; i++)
                af[i] = *(const half8*)&Qf[(wm + i * 16 + l16) * 72 + ks * 32 + quad * 8];
            #pragma unroll
            for (int j = 0; j < 2; j++)
                bfr[j] = *(const half8*)&Bs[(wn + j * 16 + l16) * 72 + ks * 32 + quad * 8];
            #pragma unroll
            for (int i = 0; i < 2; i++)
                #pragma unroll
                for (int j = 0; j < 2; j++)
                    a2[i][j] = __builtin_amdgcn_mfma_f32_16x16x32_f16(af[i], bfr[j], a2[i][j], 0, 0, 0);
        }
        #pragma unroll
        for (int i = 0; i < 2; i++)
            #pragma unroll
            for (int j = 0; j < 2; j++)
                #pragma unroll
                for (int r = 0; r < 4; r++) {
                    int rb = m0 + wm + i * 16 + quad * 4 + r;
                    int cj = jt * 64 + wn + j * 16 + l16;
                    qkb[((size_t)rb * 8 + h) * 512 + cj] = f2bf(a2[i][j][r]);
                }
    }
}

// ---------- K3: fused sims+cluster+attention; 256 blocks x 2 b, 512 threads ----------
__global__ __launch_bounds__(512) void fused_attn(const float* __restrict__ tf,
                                                  const float* __restrict__ vis_n,
                                                  const u16* __restrict__ qkb,
                                                  u16* __restrict__ u_allb,
                                                  float* __restrict__ out_cs)
{
    __shared__ __align__(16) u16 Xs[96 * 520];
    __shared__ __align__(16) u16 Qs[16 * 520];
    __shared__ __align__(16) u16 Ps[16 * 104];
    __shared__ float Sc[16 * 100];
    __shared__ float sm_[96], srt[96], linv[8];

    const int b0 = blockIdx.x * 2;
    const int t = threadIdx.x, w = t >> 6, lane = t & 63;
    const int l16 = lane & 15, quad = lane >> 4;

    // preload b0's rows: wave w owns rows w + 8k, k=0..11 (pairs for ILP)
    float4 xr[12][2];
    #pragma unroll
    for (int i = 0; i < 6; i++) {
        int m0r = w + i * 16, m1r = m0r + 8;
        const float4* pa = (const float4*)(tf + ((size_t)b0 * 96 + m0r) * 512 + lane * 8);
        const float4* pb = (const float4*)(tf + ((size_t)b0 * 96 + m1r) * 512 + lane * 8);
        xr[2*i][0]   = pa[0]; xr[2*i][1]   = pa[1];
        xr[2*i+1][0] = pb[0]; xr[2*i+1][1] = pb[1];
    }

    for (int ib = 0; ib < 2; ib++) {
        const int b = b0 + ib;
        const float4* v4 = (const float4*)(vis_n + (size_t)b * 512 + lane * 8);
        float4 va = v4[0], vb = v4[1];

        #pragma unroll
        for (int i = 0; i < 6; i++) {
            int m0r = w + i * 16, m1r = m0r + 8;
            float4 a0 = xr[2*i][0],   c0 = xr[2*i][1];
            float4 a1 = xr[2*i+1][0], c1 = xr[2*i+1][1];
            if (ib == 0) {   // prefetch next b's rows into the freed regs
                const float4* pa = (const float4*)(tf + ((size_t)(b0 + 1) * 96 + m0r) * 512 + lane * 8);
                const float4* pb = (const float4*)(tf + ((size_t)(b0 + 1) * 96 + m1r) * 512 + lane * 8);
                xr[2*i][0]   = pa[0]; xr[2*i][1]   = pa[1];
                xr[2*i+1][0] = pb[0]; xr[2*i+1][1] = pb[1];
            }
            float ss0 = a0.x*a0.x + a0.y*a0.y + a0.z*a0.z + a0.w*a0.w
                      + c0.x*c0.x + c0.y*c0.y + c0.z*c0.z + c0.w*c0.w;
            float dt0 = a0.x*va.x + a0.y*va.y + a0.z*va.z + a0.w*va.w
                      + c0.x*vb.x + c0.y*vb.y + c0.z*vb.z + c0.w*vb.w;
            float ss1 = a1.x*a1.x + a1.y*a1.y + a1.z*a1.z + a1.w*a1.w
                      + c1.x*c1.x + c1.y*c1.y + c1.z*c1.z + c1.w*c1.w;
            float dt1 = a1.x*va.x + a1.y*va.y + a1.z*va.z + a1.w*va.w
                      + c1.x*vb.x + c1.y*vb.y + c1.z*vb.z + c1.w*vb.w;
            #pragma unroll
            for (int off = 32; off; off >>= 1) {
                ss0 += __shfl_xor(ss0, off, 64);
                dt0 += __shfl_xor(dt0, off, 64);
                ss1 += __shfl_xor(ss1, off, 64);
                dt1 += __shfl_xor(dt1, off, 64);
            }
            if (lane == 0) {
                sm_[m0r] = dt0 / fmaxf(sqrtf(ss0), EPS);
                sm_[m1r] = dt1 / fmaxf(sqrtf(ss1), EPS);
            }
            uint4 pk0, pk1;
            pk0.x = pack2(a0.x, a0.y); pk0.y = pack2(a0.z, a0.w);
            pk0.z = pack2(c0.x, c0.y); pk0.w = pack2(c0.z, c0.w);
            pk1.x = pack2(a1.x, a1.y); pk1.y = pack2(a1.z, a1.w);
            pk1.z = pack2(c1.x, c1.y); pk1.w = pack2(c1.z, c1.w);
            *(uint4*)&Xs[m0r * 520 + lane * 8] = pk0;
            *(uint4*)&Xs[m1r * 520 + lane * 8] = pk1;
        }
        // Qs: wave w loads head w's qk row (already bf16)
        *(uint4*)&Qs[w * 520 + lane * 8] = *(const uint4*)(qkb + ((size_t)b * 8 + w) * 512 + lane * 8);
        __syncthreads();

        // scores: Sc[h=l16][m] = (X @ qk^T)/8 ; waves 0..5 take the 6 m-tiles
        if (w < 6) {
            f32x4 acc;
            for (int e = 0; e < 4; e++) acc[e] = 0.f;
            #pragma unroll
            for (int ks = 0; ks < 16; ks++) {
                short8 a = *(const short8*)&Xs[(w * 16 + l16) * 520 + ks * 32 + quad * 8];
                short8 q = *(const short8*)&Qs[l16 * 520 + ks * 32 + quad * 8];
                acc = __builtin_amdgcn_mfma_f32_16x16x32_bf16(a, q, acc, 0, 0, 0);
            }
            #pragma unroll
            for (int r = 0; r < 4; r++)
                Sc[l16 * 100 + w * 16 + quad * 4 + r] = acc[r] * 0.125f;
        }
        __syncthreads();

        // softmax (wave w = head w) -> Ps (unnormalized exp, bf16) + linv
        {
            float e0 = __expf(Sc[w * 100 + lane]);
            float e1 = (lane < 32) ? __expf(Sc[w * 100 + 64 + lane]) : 0.f;
            float l = wave_sum(e0 + e1);
            Ps[w * 104 + lane] = f2bf(e0);
            if (lane < 32) Ps[w * 104 + 64 + lane] = f2bf(e1);
            if (lane == 0) linv[w] = 1.0f / l;
        }
        if (t < 96) {
            float v = sm_[t]; int r = 0;
            for (int j = 0; j < 96; j++) {
                float u = sm_[j];
                r += (u > v) || (u == v && j < t);
            }
            srt[r] = v;
        }
        __syncthreads();

        // u GEMM: u[h][d] = P(8x96) @ X(96x512); 8 waves x 4 n-tiles
        #pragma unroll
        for (int jj = 0; jj < 4; jj++) {
            int n0 = (w * 4 + jj) * 16;
            f32x4 acc;
            for (int e = 0; e < 4; e++) acc[e] = 0.f;
            #pragma unroll
            for (int ks = 0; ks < 3; ks++) {
                short8 ap = *(const short8*)&Ps[l16 * 104 + ks * 32 + quad * 8];
                short8 bx;
                #pragma unroll
                for (int j = 0; j < 8; j++)
                    bx[j] = (short)Xs[(ks * 32 + quad * 8 + j) * 520 + n0 + l16];
                acc = __builtin_amdgcn_mfma_f32_16x16x32_bf16(ap, bx, acc, 0, 0, 0);
            }
            if (quad < 2) {
                #pragma unroll
                for (int r = 0; r < 4; r++) {
                    int h = quad * 4 + r;
                    u_allb[((size_t)b * 8 + h) * 512 + n0 + l16] = f2bf(acc[r] * linv[h]);
                }
            }
        }
        if (t < 3) {
            float mean = 0.f;
            #pragma unroll 8
            for (int i = 0; i < 32; i++) mean += srt[t * 32 + i];
            mean *= (1.0f / 32.0f);
            float var = 0.f;
            #pragma unroll 8
            for (int i = 0; i < 32; i++) { float d = srt[t * 32 + i] - mean; var += d * d; }
            var *= (1.0f / 31.0f);
            out_cs[b * 3 + t] = mean / (sqrtf(var) + 1e-6f);
        }
        __syncthreads();   // protect LDS before next batch overwrites
    }
}

// ---------- K4: ctx_h(512x64) = u_h(512x512) @ Wv_h(64x512)^T + bv_h, bf16 out ----------
__global__ __launch_bounds__(256) void gemm_head(const u16* __restrict__ u_allb,
                                                 const u16* __restrict__ wvb,
                                                 const float* __restrict__ bv,
                                                 u16* __restrict__ ctxb)
{
    const int h = blockIdx.y;
    const u16* A = u_allb + h * 512;                 // lda 4096
    const u16* B = wvb + (size_t)h * 64 * 512;       // 64 rows, ldb 512
    __shared__ __align__(16) u16 As[64 * 72];
    __shared__ __align__(16) u16 Bs[64 * 72];
    const int t = threadIdx.x, lane = t & 63, w = t >> 6;
    const int m0 = blockIdx.x * 64;
    const int wm = (w >> 1) * 32, wn = (w & 1) * 32;
    const int l16 = lane & 15, quad = lane >> 4;
    const int srow = t >> 3, scol = (t & 7) * 8;

    f32x4 acc[2][2];
    for (int i = 0; i < 2; i++)
        for (int j = 0; j < 2; j++)
            for (int e = 0; e < 4; e++) acc[i][j][e] = 0.f;

    for (int ko = 0; ko < 512; ko += 64) {
        __syncthreads();
        #pragma unroll
        for (int i = 0; i < 2; i++) {
            int row = i * 32 + srow;
            *(uint4*)&As[row * 72 + scol] = *(const uint4*)&A[(size_t)(m0 + row) * 4096 + ko + scol];
            *(uint4*)&Bs[row * 72 + scol] = *(const uint4*)&B[(size_t)row * 512 + ko + scol];
        }
        __syncthreads();
        #pragma unroll
        for (int ks = 0; ks < 2; ks++) {
            short8 af[2], bfr[2];
            #pragma unroll
            for (int i = 0; i < 2; i++)
                af[i] = *(const short8*)&As[(wm + i * 16 + l16) * 72 + ks * 32 + quad * 8];
            #pragma unroll
            for (int j = 0; j < 2; j++)
                bfr[j] = *(const short8*)&Bs[(wn + j * 16 + l16) * 72 + ks * 32 + quad * 8];
            #pragma unroll
            for (int i = 0; i < 2; i++)
                #pragma unroll
                for (int j = 0; j < 2; j++)
                    acc[i][j] = __builtin_amdgcn_mfma_f32_16x16x32_bf16(af[i], bfr[j], acc[i][j], 0, 0, 0);
        }
    }
    for (int i = 0; i < 2; i++) {
        int row = m0 + wm + i * 16 + quad * 4;
        for (int j = 0; j < 2; j++) {
            int col = wn + j * 16 + l16;
            float bb = bv[h * 64 + col];
            for (int r = 0; r < 4; r++)
                ctxb[(size_t)(row + r) * 512 + h * 64 + col] = f2bf(acc[i][j][r] + bb);
        }
    }
}

// ---------- K5: corrected = ctx @ Wo^T + bo; fp32 out + bf16 negsb[0:512] + row sumsq ----------
__global__ __launch_bounds__(256) void gemm_corr(const u16* __restrict__ A,
                                                 const u16* __restrict__ B,
                                                 const float* __restrict__ bias,
                                                 float* __restrict__ Cf,
                                                 u16* __restrict__ corrB,
                                                 float* __restrict__ corrSS)
{
    __shared__ __align__(16) u16 As[64 * 72];
    __shared__ __align__(16) u16 Bs[64 * 72];
    const int t = threadIdx.x, lane = t & 63, w = t >> 6;
    const int m0 = blockIdx.x * 64, n0 = blockIdx.y * 64;
    const int wm = (w >> 1) * 32, wn = (w & 1) * 32;
    const int l16 = lane & 15, quad = lane >> 4;
    const int srow = t >> 3, scol = (t & 7) * 8;

    f32x4 acc[2][2];
    for (int i = 0; i < 2; i++)
        for (int j = 0; j < 2; j++)
            for (int e = 0; e < 4; e++) acc[i][j][e] = 0.f;

    for (int ko = 0; ko < 512; ko += 64) {
        __syncthreads();
        #pragma unroll
        for (int i = 0; i < 2; i++) {
            int row = i * 32 + srow;
            *(uint4*)&As[row * 72 + scol] = *(const uint4*)&A[(size_t)(m0 + row) * 512 + ko + scol];
            *(uint4*)&Bs[row * 72 + scol] = *(const uint4*)&B[(size_t)(n0 + row) * 512 + ko + scol];
        }
        __syncthreads();
        #pragma unroll
        for (int ks = 0; ks < 2; ks++) {
            short8 af[2], bfr[2];
            #pragma unroll
            for (int i = 0; i < 2; i++)
                af[i] = *(const short8*)&As[(wm + i * 16 + l16) * 72 + ks * 32 + quad * 8];
            #pragma unroll
            for (int j = 0; j < 2; j++)
                bfr[j] = *(const short8*)&Bs[(wn + j * 16 + l16) * 72 + ks * 32 + quad * 8];
            #pragma unroll
            for (int i = 0; i < 2; i++)
                #pragma unroll
                for (int j = 0; j < 2; j++)
                    acc[i][j] = __builtin_amdgcn_mfma_f32_16x16x32_bf16(af[i], bfr[j], acc[i][j], 0, 0, 0);
        }
    }
    #pragma unroll
    for (int i = 0; i < 2; i++) {
        #pragma unroll
        for (int r = 0; r < 4; r++) {
            int row = m0 + wm + i * 16 + quad * 4 + r;
            float s = 0.f;
            #pragma unroll
            for (int j = 0; j < 2; j++) {
                int col = n0 + wn + j * 16 + l16;
                float v = acc[i][j][r] + bias[col];
                Cf[(size_t)row * 512 + col] = v;
                corrB[(size_t)row * 512 + col] = f2bf(v);
                s += v * v;
            }
            s += __shfl_xor(s, 1, 64); s += __shfl_xor(s, 2, 64);
            s += __shfl_xor(s, 4, 64); s += __shfl_xor(s, 8, 64);
            if (l16 == 0) atomicAdd(&corrSS[row], s);
        }
    }
}

// ---------- K6: generic C(MxN) = A(Mx512,bf16) @ B(Nx512,bf16)^T [+bias], fp32 out ----------
__global__ __launch_bounds__(256) void gemm64(const u16* __restrict__ A, int lda,
                                              const u16* __restrict__ B,
                                              const float* __restrict__ bias,
                                              float* __restrict__ Cf, int ldc)
{
    __shared__ __align__(16) u16 As[64 * 72];
    __shared__ __align__(16) u16 Bs[64 * 72];
    const int t = threadIdx.x, lane = t & 63, w = t >> 6;
    const int m0 = blockIdx.x * 64, n0 = blockIdx.y * 64;
    const int wm = (w >> 1) * 32, wn = (w & 1) * 32;
    const int l16 = lane & 15, quad = lane >> 4;
    const int srow = t >> 3, scol = (t & 7) * 8;

    f32x4 acc[2][2];
    for (int i = 0; i < 2; i++)
        for (int j = 0; j < 2; j++)
            for (int e = 0; e < 4; e++) acc[i][j][e] = 0.f;

    for (int ko = 0; ko < 512; ko += 64) {
        __syncthreads();
        #pragma unroll
        for (int i = 0; i < 2; i++) {
            int row = i * 32 + srow;
            *(uint4*)&As[row * 72 + scol] = *(const uint4*)&A[(size_t)(m0 + row) * lda + ko + scol];
            *(uint4*)&Bs[row * 72 + scol] = *(const uint4*)&B[(size_t)(n0 + row) * 512 + ko + scol];
        }
        __syncthreads();
        #pragma unroll
        for (int ks = 0; ks < 2; ks++) {
            short8 af[2], bfr[2];
            #pragma unroll
            for (int i = 0; i < 2; i++)
                af[i] = *(const short8*)&As[(wm + i * 16 + l16) * 72 + ks * 32 + quad * 8];
            #pragma unroll
            for (int j = 0; j < 2; j++)
                bfr[j] = *(const short8*)&Bs[(wn + j * 16 + l16) * 72 + ks * 32 + quad * 8];
            #pragma unroll
            for (int i = 0; i < 2; i++)
                #pragma unroll
                for (int j = 0; j < 2; j++)
                    acc[i][j] = __builtin_amdgcn_mfma_f32_16x16x32_bf16(af[i], bfr[j], acc[i][j], 0, 0, 0);
        }
    }
    for (int i = 0; i < 2; i++) {
        int row = m0 + wm + i * 16 + quad * 4;
        for (int j = 0; j < 2; j++) {
            int col = n0 + wn + j * 16 + l16;
            float bvv = bias ? bias[col] : 0.f;
            for (int r = 0; r < 4; r++)
                Cf[(size_t)(row + r) * ldc + col] = acc[i][j][r] + bvv;
        }
    }
}

// ---------- K7: top-5 + loss; per-wave top-5 (no sync) then single merge ----------
__global__ __launch_bounds__(256) void topk_loss(const float* __restrict__ ns,
                                                 const float* __restrict__ corrSS,
                                                 const float* __restrict__ tau_p_log,
                                                 const float* __restrict__ tau_n_log,
                                                 float* __restrict__ out_loss)
{
    __shared__ float invn[512];
    __shared__ float cv[20];
    __shared__ int   cjx[20];
    int b = blockIdx.x, t = threadIdx.x;
    int w = t >> 6, lane = t & 63;

    {
        float s0 = corrSS[t], s1 = corrSS[t + 256];
        invn[t]       = 1.0f / fmaxf(sqrtf(s0), EPS);
        invn[t + 256] = 1.0f / fmaxf(sqrtf(s1), EPS);
    }
    __syncthreads();

    const float4 raw = *(const float4*)(ns + (size_t)b * 1024 + t * 4);
    float lv[4] = {raw.x, raw.y, raw.z, raw.w};
    int   li[4] = {t * 4, t * 4 + 1, t * 4 + 2, t * 4 + 3};
    if (t < 128) {
        lv[0] *= invn[t * 4];     lv[1] *= invn[t * 4 + 1];
        lv[2] *= invn[t * 4 + 2]; lv[3] *= invn[t * 4 + 3];
    }
    #pragma unroll
    for (int i = 1; i < 4; i++) {
        float kv = lv[i]; int kx = li[i];
        int j = i - 1;
        #pragma unroll
        for (int k = 0; k < 3; k++) {
            if (j >= 0 && lv[j] < kv) { lv[j + 1] = lv[j]; li[j + 1] = li[j]; j--; }
        }
        lv[j + 1] = kv; li[j + 1] = kx;
    }
    int lp = 0;
    // per-wave top-5 via shuffle argmax, no block syncs
    #pragma unroll
    for (int rd = 0; rd < 5; rd++) {
        float mv = (lp < 4) ? lv[lp] : -1e30f;
        int   mi = (lp < 4) ? li[lp] : 0;
        int   ml = lane;
        #pragma unroll
        for (int off = 32; off; off >>= 1) {
            float ov = __shfl_xor(mv, off, 64);
            int   oi = __shfl_xor(mi, off, 64);
            int   ol = __shfl_xor(ml, off, 64);
            if (ov > mv || (ov == mv && ol < ml)) { mv = ov; mi = oi; ml = ol; }
        }
        if (lane == ml) lp++;
        if (lane == 0) { cv[w * 5 + rd] = mv; cjx[w * 5 + rd] = mi; }
    }
    __syncthreads();
    if (w == 0) {
        float v  = (lane < 20) ? cv[lane] : -1e30f;
        int   jx = (lane < 20) ? cjx[lane] : 0;
        float tn = expf(tau_n_log[0]);
        float itn = 1.0f / tn;
        float nsum = 0.f; int coll = 0;
        #pragma unroll
        for (int rd = 0; rd < 5; rd++) {
            float mv = v; int ml = lane; int mj = jx;
            #pragma unroll
            for (int off = 32; off; off >>= 1) {
                float ov = __shfl_xor(mv, off, 64);
                int   oj = __shfl_xor(mj, off, 64);
                int   ol = __shfl_xor(ml, off, 64);
                if (ov > mv || (ov == mv && ol < ml)) { mv = ov; mj = oj; ml = ol; }
            }
            int mult = (mj < 512) ? 2 : 1;
            int take = 5 - coll;
            take = (mult < take) ? mult : take;
            if (take < 0) take = 0;
            nsum += (float)take * __expf(mv * itn);
            coll += take;
            if (lane == ml) v = -1e30f;
        }
        if (lane == 0) {
            float pos = ns[(size_t)b * 1024 + b] * invn[b];   // cos(vis_n, corr_n)
            float tp = expf(tau_p_log[0]);
            float p = expf(pos / tp);
            float term = logf(p / (p + nsum + 1e-8f));
            atomicAdd(out_loss, -term * (1.0f / 512.0f));
        }
    }
}

// ---------- launch ----------
extern "C" void kernel_launch(void* const* d_in, const int* in_sizes, int n_in,
                              void* d_out, int out_size, void* d_ws, size_t ws_size,
                              hipStream_t stream) {
    const float* vis = (const float*)d_in[0];
    const float* tf  = (const float*)d_in[1];
    const float* ipw = (const float*)d_in[2];
    const float* ipb = (const float*)d_in[3];
    const float* opw = (const float*)d_in[4];
    const float* opb = (const float*)d_in[5];
    const float* tm  = (const float*)d_in[6];
    const float* tpl = (const float*)d_in[7];
    const float* tnl = (const float*)d_in[8];

    float* out       = (float*)d_out;
    float* out_loss  = out;
    float* out_corr  = out + 1;                  // (512,512)
    float* out_cs    = out + 1 + 512 * 512;      // (512,3)

    char* p = (char*)d_ws;
    auto alloc = [&](size_t bytes) { char* r = p; p += (bytes + 255) & ~(size_t)255; return r; };
    float* vis_n  = (float*)alloc(512 * 512 * 4);
    u16*   vis_nb = (u16*)  alloc(512 * 512 * 2);
    u16*   vis_b  = (u16*)  alloc(512 * 512 * 2);
    u16*   wqb    = (u16*)  alloc(512 * 512 * 2);
    u16*   wvb    = (u16*)  alloc(512 * 512 * 2);
    u16*   wob    = (u16*)  alloc(512 * 512 * 2);
    u16*   wkT    = (u16*)  alloc(512 * 512 * 2);
    u16*   qkb    = (u16*)  alloc((size_t)512 * 8 * 512 * 2);
    u16*   u_allb = (u16*)  alloc((size_t)512 * 8 * 512 * 2);
    u16*   ctxb   = (u16*)  alloc(512 * 512 * 2);
    u16*   negsb  = (u16*)  alloc(1024 * 512 * 2);
    float* ns     = (float*)alloc(512 * 1024 * 4);
    float* corrSS = (float*)alloc(512 * 4);

    const float* bv = ipb + 2 * 512;

    prep<<<1088, 256, 0, stream>>>(vis, ipw, opw, tm, vis_n, vis_nb, vis_b,
                                   wqb, wvb, wob, negsb, wkT, corrSS, out_loss);
    qqk<<<dim3(8, 8), 256, 0, stream>>>(vis_b, wqb, ipb, wkT, qkb);
    fused_attn<<<256, 512, 0, stream>>>(tf, vis_n, qkb, u_allb, out_cs);
    gemm_head<<<dim3(8, 8), 256, 0, stream>>>(u_allb, wvb, bv, ctxb);
    gemm_corr<<<dim3(8, 8), 256, 0, stream>>>(ctxb, wob, opb, out_corr, negsb, corrSS);
    gemm64<<<dim3(8, 16), 256, 0, stream>>>(vis_nb, 512, negsb, nullptr, ns, 1024);
    topk_loss<<<512, 256, 0, stream>>>(ns, corrSS, tpl, tnl, out_loss);
}